// Round 11
// baseline (114.535 us; speedup 1.0000x reference)
//
#include <hip/hip_runtime.h>
#include <hip/hip_bf16.h>

// ChebyKANLinear: y[b,j] = sum_i sum_k T_k(tanh(x[b,i])) * C[i,j,k]
// GEMM: M=16384, N=512, K=4608 (kflat = k*512 + i), k=0 folded into S0[j].
// v10: producer/consumer phase split per block.
//   - produce: basis computed ONCE per block per ic (f32 recurrence, bf16
//     frags) into 64KB LDS A-tile in MFMA-fragment layout, XOR slot swizzle
//     s' = s ^ ((row>>1)&3): consumer reads conflict-free, writes <=2-way.
//   - consume: per kstep only 4 ds_read_b128 + 4 B-loads + 16 MFMA (no VALU).
//   - raw s_barrier + lgkmcnt(0) only (B prefetch never drained; T4).
//   - 2 blocks/CU: block A's produce overlaps block B's consume (m114).

typedef __bf16 bf16x8 __attribute__((ext_vector_type(8)));
typedef float  f32x4  __attribute__((ext_vector_type(4)));

#define DIM  512
#define KDEG 9
#define NK   8               // k = 1..8 (k=0 folded into S0)
#define NIC  16
#define SLAB (4 * DIM * 8)   // 16384 bf16 per (k,ic) slab of W2

// ---- pack: C[i][j][k] -> W2[(k*16+ic)][s][j][e] (bf16), i = ic*32 + s*8 + e ----
__global__ void pack_w_kernel(const float* __restrict__ coeffs,
                              __bf16* __restrict__ W2) {
    int t  = blockIdx.x * blockDim.x + threadIdx.x;   // 32768 threads
    int j  = t & (DIM - 1);
    int s  = (t >> 9) & 3;
    int ic = t >> 11;

    bf16x8 v[KDEG];
#pragma unroll
    for (int e = 0; e < 8; ++e) {
        int i = ic * 32 + s * 8 + e;
        const float* src = coeffs + ((size_t)i * DIM + j) * KDEG;
#pragma unroll
        for (int k = 0; k < KDEG; ++k)
            v[k][e] = (__bf16)src[k];
    }
#pragma unroll
    for (int k = 0; k < KDEG; ++k) {
        size_t off = (size_t)(k * 16 + ic) * SLAB + ((size_t)s * DIM + j) * 8;
        *reinterpret_cast<bf16x8*>(W2 + off) = v[k];
    }
}

// ---- S0[j] = sum_i C[i][j][0] (f32), stored into W2's unused k=0 slab ----
__global__ void s0_kernel(const float* __restrict__ coeffs,
                          float* __restrict__ S0) {
    const int j    = blockIdx.x;      // 512 blocks
    const int lane = threadIdx.x;     // 64
    float s = 0.0f;
#pragma unroll
    for (int i = lane; i < DIM; i += 64)
        s += coeffs[((size_t)i * DIM + j) * KDEG];
#pragma unroll
    for (int off = 32; off > 0; off >>= 1)
        s += __shfl_down(s, off, 64);
    if (lane == 0) S0[j] = s;
}

// ---------------- fused: produce(basis->LDS) / consume(MFMA) ----------------
__global__ __launch_bounds__(256, 2) void cheby_gemm_kernel(
    const float* __restrict__ x,
    const __bf16* __restrict__ W2,
    float* __restrict__ out)
{
    // A-tile: [kk][row][slot][8] bf16, 64 KB. slot stored XOR-swizzled.
    __shared__ __bf16 A_lds[NK][128][4][8];

    const int tid  = threadIdx.x;
    const int lane = tid & 63;
    const int wid  = tid >> 6;      // 0..3
    const int wr   = wid >> 1;      // 0..1  m-half (64 rows)
    const int wc   = wid & 1;       // 0..1  n-half (64 cols)
    const int l15  = lane & 15;
    const int l4   = lane >> 4;     // 0..3
    const int bm   = blockIdx.y * 128;
    const int bn   = blockIdx.x * 128;

    // ---- producer mapping: wave wid owns rows wid*32..+31; 2 lanes/row ----
    const int prow = lane >> 1;            // 0..31
    const int ps   = (lane & 1) * 2;       // slot base 0 or 2
    const int grow = wid * 32 + prow;      // block-row 0..127
    const int rsw  = (grow >> 1) & 3;      // slot swizzle for this row
    const float* xp = x + (size_t)(bm + grow) * DIM + ps * 8;
    __bf16* wp0 = &A_lds[0][grow][ps ^ rsw][0];
    __bf16* wp1 = &A_lds[0][grow][(ps + 1) ^ rsw][0];

    // ---- consumer A base: row = wr*64 + mf*16 + l15, logical slot l4 ----
    const __bf16* abase = &A_lds[0][wr * 64 + l15][l4 ^ ((l15 >> 1) & 3)][0];

    // ---- B lane base (register-streamed from L2-resident W2) ----
    const __bf16* wbase = W2 + ((size_t)l4 * DIM + bn + wc * 64 + l15) * 8;

    // acc init from S0 (the k=0 term)
    const float* S0 = (const float*)W2;
    f32x4 acc[4][4];
#pragma unroll
    for (int nf = 0; nf < 4; ++nf) {
        float s0v = S0[bn + wc * 64 + nf * 16 + l15];
#pragma unroll
        for (int mf = 0; mf < 4; ++mf)
#pragma unroll
            for (int r = 0; r < 4; ++r)
                acc[mf][nf][r] = s0v;
    }

    // B 2-set register buffer; prologue: (k=1, ic=0) -> set 0. 8 ksteps/ic
    // (even) -> parity-safe across ic boundaries.
    bf16x8 bq[2][4];
#pragma unroll
    for (int nf = 0; nf < 4; ++nf)
        bq[0][nf] = *reinterpret_cast<const bf16x8*>(
            wbase + (size_t)16 * SLAB + nf * 128);

    // x regs for ic=0 (16 elems: slots ps, ps+1)
    f32x4 xq[4];
#pragma unroll
    for (int q = 0; q < 4; ++q)
        xq[q] = *reinterpret_cast<const f32x4*>(xp + q * 4);

    for (int ic = 0; ic < NIC; ++ic) {
        // ================= produce: basis -> LDS =================
        float Tk[16], Tm[16], t2[16];
#pragma unroll
        for (int e = 0; e < 16; ++e) {
            float xv = xq[e >> 2][e & 3];
            float p  = __builtin_amdgcn_exp2f(xv * 2.8853900817779268f);
            float t  = 1.0f - 2.0f * __builtin_amdgcn_rcpf(p + 1.0f);
            Tk[e] = t;          // T_1
            t2[e] = t + t;
            Tm[e] = 1.0f;       // T_0
        }
        // prefetch next ic's x (hidden under produce+consume)
        if (ic + 1 < NIC) {
#pragma unroll
            for (int q = 0; q < 4; ++q)
                xq[q] = *reinterpret_cast<const f32x4*>(xp + (ic + 1) * 32 + q * 4);
        }
#pragma unroll
        for (int kk = 0; kk < NK; ++kk) {    // stores T_{kk+1}
            bf16x8 v0, v1;
#pragma unroll
            for (int e = 0; e < 8; ++e) {
                v0[e] = (__bf16)Tk[e];
                v1[e] = (__bf16)Tk[8 + e];
            }
            *reinterpret_cast<bf16x8*>(wp0 + kk * 4096) = v0;
            *reinterpret_cast<bf16x8*>(wp1 + kk * 4096) = v1;
            if (kk < NK - 1) {
#pragma unroll
                for (int e = 0; e < 16; ++e) {
                    float Tn = __builtin_fmaf(t2[e], Tk[e], -Tm[e]);
                    Tm[e] = Tk[e];
                    Tk[e] = Tn;
                }
            }
        }
        asm volatile("s_waitcnt lgkmcnt(0)" ::: "memory");
        __builtin_amdgcn_s_barrier();
        asm volatile("" ::: "memory");

        // ================= consume: 8 ksteps of pure MFMA =================
#pragma unroll
        for (int kk = 0; kk < NK; ++kk) {    // consuming k = kk+1
            const int cs = kk & 1;
            // prefetch next kstep's B into the other set (never drained)
            if ((kk < NK - 1) || (ic + 1 < NIC)) {
                const int nk  = (kk < NK - 1) ? kk + 2 : 1;    // k index 1..8
                const int nic = (kk < NK - 1) ? ic : ic + 1;
                const __bf16* np = wbase + (size_t)(nk * 16 + nic) * SLAB;
#pragma unroll
                for (int nf = 0; nf < 4; ++nf)
                    bq[cs ^ 1][nf] = *reinterpret_cast<const bf16x8*>(np + nf * 128);
            }

            // A frags from LDS (conflict-free swizzled reads)
            bf16x8 af[4];
#pragma unroll
            for (int mf = 0; mf < 4; ++mf)
                af[mf] = *reinterpret_cast<const bf16x8*>(
                    abase + kk * 4096 + mf * 512);

            // 16 MFMA
#pragma unroll
            for (int nf = 0; nf < 4; ++nf)
#pragma unroll
                for (int mf = 0; mf < 4; ++mf)
                    acc[mf][nf] = __builtin_amdgcn_mfma_f32_16x16x32_bf16(
                        af[mf], bq[cs][nf], acc[mf][nf], 0, 0, 0);
        }
        __builtin_amdgcn_s_barrier();   // reads done -> next produce may overwrite
        asm volatile("" ::: "memory");
    }

    // ---- epilogue: C/D layout col=lane&15, row=(lane>>4)*4+r ----
#pragma unroll
    for (int mf = 0; mf < 4; ++mf)
#pragma unroll
        for (int r = 0; r < 4; ++r) {
            const int row = bm + wr * 64 + mf * 16 + l4 * 4 + r;
            float* orow = out + (size_t)row * DIM + bn + wc * 64 + l15;
#pragma unroll
            for (int nf = 0; nf < 4; ++nf)
                orow[nf * 16] = acc[mf][nf][r];
        }
}

extern "C" void kernel_launch(void* const* d_in, const int* in_sizes, int n_in,
                              void* d_out, int out_size, void* d_ws, size_t ws_size,
                              hipStream_t stream) {
    const float* x      = (const float*)d_in[0];   // (16384, 512)
    const float* coeffs = (const float*)d_in[1];   // (512, 512, 9)
    float* out          = (float*)d_out;           // (16384, 512)
    __bf16* W2          = (__bf16*)d_ws;           // 144*16384 bf16 = 4.7MB

    pack_w_kernel<<<(DIM * 64) / 256, 256, 0, stream>>>(coeffs, W2);
    // S0 into the (GEMM-unused) k=0 slab region of W2
    s0_kernel<<<DIM, 64, 0, stream>>>(coeffs, (float*)W2);

    // grid = (N/128, M/128) = (4, 128) = 512 blocks = 2/CU (LDS 64KB each)
    cheby_gemm_kernel<<<dim3(4, 128), 256, 0, stream>>>(x, W2, out);
}